// Round 3
// baseline (684.419 us; speedup 1.0000x reference)
//
#include <hip/hip_runtime.h>
#include <stdint.h>

#define N_NODES 20000
#define N_EDGES 320000
#define EMB     256
#define D_IN    300
#define KPAD0   320   // D_IN padded to multiple of 32

typedef __attribute__((ext_vector_type(8))) short s16x8;   // 8 bf16 operand (4 VGPRs)
typedef __attribute__((ext_vector_type(4))) float f32x4;

__device__ __forceinline__ float bf2f(unsigned short u) {
    union { unsigned u; float f; } x; x.u = ((unsigned)u) << 16; return x.f;
}
__device__ __forceinline__ unsigned short f2bf(float f) {
    union { float f; unsigned u; } x; x.f = f;
    unsigned r = x.u + 0x7fffu + ((x.u >> 16) & 1u);   // RNE
    return (unsigned short)(r >> 16);
}
// split v = hi + lo (each bf16), |err| <= 2^-18 |v|
__device__ __forceinline__ void split_bf(float v, unsigned short& h, unsigned short& l) {
    h = f2bf(v);
    l = f2bf(v - bf2f(h));
}

// ---------------- CSR build ----------------

__global__ void k_init(int* deg, int* cursor, int n) {
    int i = blockIdx.x * 256 + threadIdx.x;
    if (i < n) { deg[i] = 0; cursor[i] = 0; }
}

__global__ void k_deg(const int* __restrict__ dst, int* __restrict__ deg, int e) {
    int i = blockIdx.x * 256 + threadIdx.x;
    if (i < e) atomicAdd(&deg[dst[i]], 1);
}

__global__ void k_dinv(const int* __restrict__ deg, float* __restrict__ dinv, int n) {
    int i = blockIdx.x * 256 + threadIdx.x;
    if (i < n) dinv[i] = rsqrtf((float)(deg[i] + 1));   // +1 self-loop
}

// single-block exclusive scan over deg -> row_off[0..n]
__global__ void k_scan(const int* __restrict__ deg, int* __restrict__ row_off, int n) {
    __shared__ int sums[1024];
    int tid = threadIdx.x;
    const int chunk = (n + 1023) / 1024;
    int start = tid * chunk;
    int end   = start + chunk; if (end > n) end = n; if (start > n) start = n;
    int s = 0;
    for (int i = start; i < end; ++i) s += deg[i];
    sums[tid] = s;
    __syncthreads();
    for (int off = 1; off < 1024; off <<= 1) {
        int v = (tid >= off) ? sums[tid - off] : 0;
        __syncthreads();
        sums[tid] += v;
        __syncthreads();
    }
    int excl = (tid == 0) ? 0 : sums[tid - 1];
    for (int i = start; i < end; ++i) { row_off[i] = excl; excl += deg[i]; }
    if (tid == 1023) row_off[n] = excl;
}

__global__ void k_scatter(const int* __restrict__ src, const int* __restrict__ dst,
                          const int* __restrict__ row_off, int* __restrict__ cursor,
                          const float* __restrict__ dinv,
                          int* __restrict__ csr_src, float* __restrict__ csr_norm, int e) {
    int i = blockIdx.x * 256 + threadIdx.x;
    if (i >= e) return;
    int s = src[i], d = dst[i];
    int pos = row_off[d] + atomicAdd(&cursor[d], 1);
    csr_src[pos]  = s;
    csr_norm[pos] = dinv[s] * dinv[d];
}

// W f32 [K][256] -> Wt hi/lo bf16 [256][Kpad], zero-padded beyond K
__global__ void k_wsplit(const float* __restrict__ W,
                         unsigned short* __restrict__ Wth,
                         unsigned short* __restrict__ Wtl, int K, int Kpad) {
    int idx = blockIdx.x * 256 + threadIdx.x;
    if (idx >= EMB * Kpad) return;
    int n = idx / Kpad, k = idx - n * Kpad;
    float v = (k < K) ? W[k * EMB + n] : 0.f;
    unsigned short h, l;
    split_bf(v, h, l);
    Wth[idx] = h; Wtl[idx] = l;
}

// ---------------- split-bf16 MFMA GEMM ----------------
// C[M,256] = A[M,K] @ W.  A either f32 (split in-register) or bf16 hi/lo pair.
// block = 256 threads = 4 waves; block tile 32 rows x 256 cols; wave tile 32x64.
// (32-row tile: 625 blocks -> 2500 waves for latency hiding; round-2's 64-row
//  tile gave only 1252 waves ≈ 1.2/SIMD.)
// MFMA 16x16x32 bf16 layouts (HW-verified):
//   A: row = lane&15, k = (lane>>4)*8 + j
//   B: col = lane&15, k = (lane>>4)*8 + j   (read from W^T rows)
//   C/D: col = lane&15, row = (lane>>4)*4 + reg

#define MT 2   // 16-row m-subtiles per wave

__global__ __launch_bounds__(256) void k_gemm(
    const float* __restrict__ Af32,          // non-null => f32 A path
    const unsigned short* __restrict__ Ah,   // pair A path
    const unsigned short* __restrict__ Al,
    int M, int Astride, int Ksteps, int Kpad,
    const unsigned short* __restrict__ Wth,
    const unsigned short* __restrict__ Wtl,
    const float* __restrict__ bias, int relu,
    float* __restrict__ Cf,                  // non-null => f32 out
    unsigned short* __restrict__ Ch,         // else pair out
    unsigned short* __restrict__ Cl)
{
    int tid  = threadIdx.x;
    int lane = tid & 63, wave = tid >> 6;
    int quad = lane >> 4, l16 = lane & 15;
    int m_base = blockIdx.x * (MT * 16);

    f32x4 acc[MT][4];
#pragma unroll
    for (int mt = 0; mt < MT; ++mt)
#pragma unroll
        for (int nt = 0; nt < 4; ++nt) acc[mt][nt] = (f32x4){0.f, 0.f, 0.f, 0.f};

    int mrow[MT];
#pragma unroll
    for (int mt = 0; mt < MT; ++mt) {
        int m = m_base + mt * 16 + l16;
        if (m >= M) m = M - 1;               // clamp; OOB rows never stored
        mrow[mt] = m;
    }
    const unsigned short* bh_row[4];
    const unsigned short* bl_row[4];
#pragma unroll
    for (int nt = 0; nt < 4; ++nt) {
        int nn = wave * 64 + nt * 16 + l16;
        bh_row[nt] = Wth + (size_t)nn * Kpad;
        bl_row[nt] = Wtl + (size_t)nn * Kpad;
    }

    for (int ks = 0; ks < Ksteps; ++ks) {
        int k0 = ks * 32 + quad * 8;
        s16x8 ah[MT], al[MT], bh[4], bl[4];
#pragma unroll
        for (int nt = 0; nt < 4; ++nt) {
            bh[nt] = *(const s16x8*)(bh_row[nt] + k0);
            bl[nt] = *(const s16x8*)(bl_row[nt] + k0);
        }
        if (Af32) {
#pragma unroll
            for (int mt = 0; mt < MT; ++mt) {
                const float* arow = Af32 + (size_t)mrow[mt] * Astride;
                float fv[8];
                bool last = (mrow[mt] == M - 1) && (k0 + 8 > Astride);
                if (last) {
#pragma unroll
                    for (int j = 0; j < 8; ++j) {
                        int kk = k0 + j;
                        fv[j] = (kk < Astride) ? arow[kk] : 0.f;
                    }
                } else {
                    float4 f0 = *(const float4*)(arow + k0);
                    float4 f1 = *(const float4*)(arow + k0 + 4);
                    fv[0] = f0.x; fv[1] = f0.y; fv[2] = f0.z; fv[3] = f0.w;
                    fv[4] = f1.x; fv[5] = f1.y; fv[6] = f1.z; fv[7] = f1.w;
                }
                s16x8 hv, lv;
#pragma unroll
                for (int j = 0; j < 8; ++j) {
                    unsigned short h, l;
                    split_bf(fv[j], h, l);
                    hv[j] = (short)h; lv[j] = (short)l;
                }
                ah[mt] = hv; al[mt] = lv;
            }
        } else {
#pragma unroll
            for (int mt = 0; mt < MT; ++mt) {
                const unsigned short* ar_h = Ah + (size_t)mrow[mt] * Astride;
                const unsigned short* ar_l = Al + (size_t)mrow[mt] * Astride;
                ah[mt] = *(const s16x8*)(ar_h + k0);
                al[mt] = *(const s16x8*)(ar_l + k0);
            }
        }
#pragma unroll
        for (int mt = 0; mt < MT; ++mt)
#pragma unroll
            for (int nt = 0; nt < 4; ++nt) {
                acc[mt][nt] = __builtin_amdgcn_mfma_f32_16x16x32_bf16(
                    ah[mt], bh[nt], acc[mt][nt], 0, 0, 0);
                acc[mt][nt] = __builtin_amdgcn_mfma_f32_16x16x32_bf16(
                    ah[mt], bl[nt], acc[mt][nt], 0, 0, 0);
                acc[mt][nt] = __builtin_amdgcn_mfma_f32_16x16x32_bf16(
                    al[mt], bh[nt], acc[mt][nt], 0, 0, 0);
            }
    }

#pragma unroll
    for (int mt = 0; mt < MT; ++mt) {
        int rbase = m_base + mt * 16 + quad * 4;
#pragma unroll
        for (int r = 0; r < 4; ++r) {
            int row = rbase + r;
            if (row >= M) continue;
#pragma unroll
            for (int nt = 0; nt < 4; ++nt) {
                int col = wave * 64 + nt * 16 + l16;
                float v = acc[mt][nt][r];
                if (bias) v += bias[col];
                if (relu) v = fmaxf(v, 0.f);
                size_t o = (size_t)row * EMB + col;
                if (Cf) {
                    Cf[o] = v;
                } else {
                    unsigned short h, l;
                    split_bf(v, h, l);
                    Ch[o] = h; Cl[o] = l;
                }
            }
        }
    }
}

// ---------------- Aggregation (dim-sliced, XCD-pinned) ----------------
// out[i] = bias + dinv[i]^2*h[i] + sum_j norm_j*h[src_j]; optional relu; pair out.
// slice = blockIdx & 7 matches the round-robin block->XCD mapping, so each
// XCD's L2 only sees a 20000 x 32 x 4B = 2.56 MB slice of h -> L2-resident
// gathers (round-2 full-row gathers missed L2: 143 MB HBM FETCH per dispatch).
// Each half-wave (32 lanes) = one node's 32-dim slice; 128 B coalesced gathers.

__global__ __launch_bounds__(256) void k_agg(
    const float* __restrict__ h,
    const int* __restrict__ row_off, const int* __restrict__ csr_src,
    const float* __restrict__ csr_norm, const float* __restrict__ dinv,
    const float* __restrict__ bias, int relu,
    unsigned short* __restrict__ Oh, unsigned short* __restrict__ Ol)
{
    int slice = blockIdx.x & 7;
    int node  = (blockIdx.x >> 3) * 8 + (threadIdx.x >> 5);
    if (node >= N_NODES) return;
    int d = slice * 32 + (threadIdx.x & 31);

    float dv  = dinv[node];
    float acc = bias[d] + dv * dv * h[(size_t)node * EMB + d];

    int jbeg = row_off[node], jend = row_off[node + 1];
    for (int j = jbeg; j < jend; ++j) {
        int   s = csr_src[j];      // broadcast (same addr across half-wave)
        float w = csr_norm[j];
        acc += w * h[(size_t)s * EMB + d];
    }
    if (relu) acc = fmaxf(acc, 0.f);
    size_t o = (size_t)node * EMB + d;
    unsigned short hh, ll;
    split_bf(acc, hh, ll);
    Oh[o] = hh; Ol[o] = ll;
}

// ---------------- launch ----------------

extern "C" void kernel_launch(void* const* d_in, const int* in_sizes, int n_in,
                              void* d_out, int out_size, void* d_ws, size_t ws_size,
                              hipStream_t stream) {
    const float* x  = (const float*)d_in[0];
    const int*   ei = (const int*)d_in[1];
    const int* src = ei;
    const int* dst = ei + N_EDGES;

    const float* w[6] = {
        (const float*)d_in[2], (const float*)d_in[4], (const float*)d_in[6],
        (const float*)d_in[8], (const float*)d_in[10], (const float*)d_in[12] };
    const float* b[6] = {
        (const float*)d_in[3], (const float*)d_in[5], (const float*)d_in[7],
        (const float*)d_in[9], (const float*)d_in[11], (const float*)d_in[13] };

    char* wsp = (char*)d_ws;
    auto alloc = [&](size_t bytes) {
        char* p = wsp; wsp += (bytes + 255) & ~(size_t)255; return p;
    };
    int*   deg      = (int*)alloc(N_NODES * 4);
    int*   cursor   = (int*)alloc(N_NODES * 4);
    int*   row_off  = (int*)alloc((N_NODES + 1) * 4);
    int*   csr_src  = (int*)alloc(N_EDGES * 4);
    float* csr_norm = (float*)alloc(N_EDGES * 4);
    float* dinv     = (float*)alloc(N_NODES * 4);
    unsigned short* wth[6];
    unsigned short* wtl[6];
    wth[0] = (unsigned short*)alloc(EMB * KPAD0 * 2);
    wtl[0] = (unsigned short*)alloc(EMB * KPAD0 * 2);
    for (int i = 1; i < 6; ++i) {
        wth[i] = (unsigned short*)alloc(EMB * EMB * 2);
        wtl[i] = (unsigned short*)alloc(EMB * EMB * 2);
    }
    unsigned short* HPh = (unsigned short*)alloc((size_t)N_NODES * EMB * 2);
    unsigned short* HPl = (unsigned short*)alloc((size_t)N_NODES * EMB * 2);
    float* F = (float*)d_out;   // f32 scratch == final output buffer

    const int NB_N = (N_NODES + 255) / 256;   // 79
    const int NB_E = (N_EDGES + 255) / 256;   // 1250
    const int MB   = (N_NODES + MT * 16 - 1) / (MT * 16);   // 625
    const int AGB  = ((N_NODES + 7) / 8) * 8;               // 20000 blocks

    // CSR build
    k_init<<<NB_N, 256, 0, stream>>>(deg, cursor, N_NODES);
    k_deg<<<NB_E, 256, 0, stream>>>(dst, deg, N_EDGES);
    k_dinv<<<NB_N, 256, 0, stream>>>(deg, dinv, N_NODES);
    k_scan<<<1, 1024, 0, stream>>>(deg, row_off, N_NODES);
    k_scatter<<<NB_E, 256, 0, stream>>>(src, dst, row_off, cursor, dinv,
                                        csr_src, csr_norm, N_EDGES);

    // weight transpose + split
    k_wsplit<<<(EMB * KPAD0 + 255) / 256, 256, 0, stream>>>(w[0], wth[0], wtl[0], D_IN, KPAD0);
    for (int i = 1; i < 6; ++i)
        k_wsplit<<<(EMB * EMB) / 256, 256, 0, stream>>>(w[i], wth[i], wtl[i], EMB, EMB);

    // conv0: x @ W0 -> F ; aggregate(+b0, relu) -> HP pair
    k_gemm<<<MB, 256, 0, stream>>>(x, nullptr, nullptr, N_NODES, D_IN, KPAD0 / 32, KPAD0,
                                   wth[0], wtl[0], nullptr, 0, F, nullptr, nullptr);
    k_agg<<<AGB, 256, 0, stream>>>(F, row_off, csr_src, csr_norm, dinv,
                                   b[0], 1, HPh, HPl);
    // conv1
    k_gemm<<<MB, 256, 0, stream>>>(nullptr, HPh, HPl, N_NODES, EMB, EMB / 32, EMB,
                                   wth[1], wtl[1], nullptr, 0, F, nullptr, nullptr);
    k_agg<<<AGB, 256, 0, stream>>>(F, row_off, csr_src, csr_norm, dinv,
                                   b[1], 1, HPh, HPl);
    // conv2 (no relu after agg)
    k_gemm<<<MB, 256, 0, stream>>>(nullptr, HPh, HPl, N_NODES, EMB, EMB / 32, EMB,
                                   wth[2], wtl[2], nullptr, 0, F, nullptr, nullptr);
    k_agg<<<AGB, 256, 0, stream>>>(F, row_off, csr_src, csr_norm, dinv,
                                   b[2], 0, HPh, HPl);
    // mlp1, mlp2: pair in/out in-place (block-row ownership makes this safe)
    k_gemm<<<MB, 256, 0, stream>>>(nullptr, HPh, HPl, N_NODES, EMB, EMB / 32, EMB,
                                   wth[3], wtl[3], b[3], 1, nullptr, HPh, HPl);
    k_gemm<<<MB, 256, 0, stream>>>(nullptr, HPh, HPl, N_NODES, EMB, EMB / 32, EMB,
                                   wth[4], wtl[4], b[4], 1, nullptr, HPh, HPl);
    // mlp3 -> d_out f32
    k_gemm<<<MB, 256, 0, stream>>>(nullptr, HPh, HPl, N_NODES, EMB, EMB / 32, EMB,
                                   wth[5], wtl[5], b[5], 0, F, nullptr, nullptr);
}

// Round 4
// 488.650 us; speedup vs baseline: 1.4006x; 1.4006x over previous
//
#include <hip/hip_runtime.h>
#include <stdint.h>

#define N_NODES 20000
#define N_EDGES 320000
#define EMB     256
#define D_IN    300
#define KPAD0   320   // D_IN padded to multiple of 32
#define SROW    260   // LDS row stride in floats (multiple of 4 -> 16B-aligned float4)

typedef __attribute__((ext_vector_type(8))) short s16x8;   // 8 bf16 operand (4 VGPRs)
typedef __attribute__((ext_vector_type(4))) float f32x4;

static __device__ __forceinline__ float bf2f(unsigned short u) {
    union { unsigned u; float f; } x; x.u = ((unsigned)u) << 16; return x.f;
}
static __device__ __forceinline__ unsigned short f2bf(float f) {
    union { float f; unsigned u; } x; x.f = f;
    unsigned r = x.u + 0x7fffu + ((x.u >> 16) & 1u);   // RNE
    return (unsigned short)(r >> 16);
}
// split v = hi + lo (each bf16), |err| <= 2^-18 |v|
static __device__ __forceinline__ void split_bf(float v, unsigned short& h, unsigned short& l) {
    h = f2bf(v);
    l = f2bf(v - bf2f(h));
}
static __device__ __forceinline__ void split8(const float* fv, s16x8& hi, s16x8& lo) {
#pragma unroll
    for (int j = 0; j < 8; ++j) {
        unsigned short h, l;
        split_bf(fv[j], h, l);
        hi[j] = (short)h; lo[j] = (short)l;
    }
}

// ---------------- CSR build (4 dispatches) ----------------

__global__ void k_init(int* deg, int* cursor, int n) {
    int i = blockIdx.x * 256 + threadIdx.x;
    if (i < n) { deg[i] = 0; cursor[i] = 0; }
}

__global__ void k_deg(const int* __restrict__ dst, int* __restrict__ deg, int e) {
    int i = blockIdx.x * 256 + threadIdx.x;
    if (i < e) atomicAdd(&deg[dst[i]], 1);
}

// single-block: exclusive scan over deg -> row_off[0..n], plus dinv = rsqrt(deg+1)
__global__ void k_scan(const int* __restrict__ deg, int* __restrict__ row_off,
                       float* __restrict__ dinv, int n) {
    __shared__ int sums[1024];
    int tid = threadIdx.x;
    const int chunk = (n + 1023) / 1024;
    int start = tid * chunk;
    int end   = start + chunk; if (end > n) end = n; if (start > n) start = n;
    int s = 0;
    for (int i = start; i < end; ++i) {
        s += deg[i];
        dinv[i] = rsqrtf((float)(deg[i] + 1));   // +1 self-loop
    }
    sums[tid] = s;
    __syncthreads();
    for (int off = 1; off < 1024; off <<= 1) {
        int v = (tid >= off) ? sums[tid - off] : 0;
        __syncthreads();
        sums[tid] += v;
        __syncthreads();
    }
    int excl = (tid == 0) ? 0 : sums[tid - 1];
    for (int i = start; i < end; ++i) { row_off[i] = excl; excl += deg[i]; }
    if (tid == 1023) row_off[n] = excl;
}

__global__ void k_scatter(const int* __restrict__ src, const int* __restrict__ dst,
                          const int* __restrict__ row_off, int* __restrict__ cursor,
                          const float* __restrict__ dinv,
                          int* __restrict__ csr_src, float* __restrict__ csr_norm, int e) {
    int i = blockIdx.x * 256 + threadIdx.x;
    if (i >= e) return;
    int s = src[i], d = dst[i];
    int pos = row_off[d] + atomicAdd(&cursor[d], 1);
    csr_src[pos]  = s;
    csr_norm[pos] = dinv[s] * dinv[d];
}

// ---------------- batched weight transpose+split (1 dispatch for all 6) ----------------

struct WSplitArgs {
    const float* w[6];
    unsigned short* th[6];
    unsigned short* tl[6];
};

__global__ void k_wsplit_all(WSplitArgs a) {
#pragma unroll
    for (int l = 0; l < 6; ++l) {
        const int K    = (l == 0) ? D_IN  : EMB;
        const int Kpad = (l == 0) ? KPAD0 : EMB;
        const int tot  = EMB * Kpad;
        for (int idx = blockIdx.x * 256 + threadIdx.x; idx < tot; idx += gridDim.x * 256) {
            int n = idx / Kpad, k = idx - n * Kpad;
            float v = (k < K) ? a.w[l][k * EMB + n] : 0.f;
            unsigned short h, lo;
            split_bf(v, h, lo);
            a.th[l][idx] = h; a.tl[l][idx] = lo;
        }
    }
}

// ---------------- conv0 GEMM: C[M,256] = x[M,300] @ W0, f32 in/out ----------------
// block = 4 waves; block tile 32 rows x 256 cols; wave tile 32x64 (MT=2).
// MFMA 16x16x32 bf16 layouts (HW-verified):
//   A: row = lane&15, k = (lane>>4)*8 + j
//   B: col = lane&15, k = (lane>>4)*8 + j   (read from W^T rows)
//   C/D: col = lane&15, row = (lane>>4)*4 + reg

__global__ __launch_bounds__(256) void k_gemm0(
    const float* __restrict__ A,
    const unsigned short* __restrict__ Wth,
    const unsigned short* __restrict__ Wtl,
    float* __restrict__ C)
{
    int tid  = threadIdx.x;
    int lane = tid & 63, wave = tid >> 6;
    int quad = lane >> 4, l16 = lane & 15;
    int m_base = blockIdx.x * 32;

    f32x4 acc[2][4];
#pragma unroll
    for (int mt = 0; mt < 2; ++mt)
#pragma unroll
        for (int nt = 0; nt < 4; ++nt) acc[mt][nt] = (f32x4){0.f, 0.f, 0.f, 0.f};

    for (int ks = 0; ks < KPAD0 / 32; ++ks) {
        int k0 = ks * 32 + quad * 8;
        s16x8 ah[2], al[2], bh[4], bl[4];
#pragma unroll
        for (int nt = 0; nt < 4; ++nt) {
            int nn = wave * 64 + nt * 16 + l16;
            bh[nt] = *(const s16x8*)(Wth + (size_t)nn * KPAD0 + k0);
            bl[nt] = *(const s16x8*)(Wtl + (size_t)nn * KPAD0 + k0);
        }
#pragma unroll
        for (int mt = 0; mt < 2; ++mt) {
            int row = m_base + mt * 16 + l16;
            const float* ar = A + (size_t)row * D_IN;
            float fv[8];
            if (row == N_NODES - 1 && k0 + 8 > D_IN) {
#pragma unroll
                for (int j = 0; j < 8; ++j) {
                    int kk = k0 + j;
                    fv[j] = (kk < D_IN) ? ar[kk] : 0.f;
                }
            } else {
                // k past 299 reads next row's data; harmless: Wt zero-padded there.
                *(float4*)(fv)     = *(const float4*)(ar + k0);
                *(float4*)(fv + 4) = *(const float4*)(ar + k0 + 4);
            }
            split8(fv, ah[mt], al[mt]);
        }
#pragma unroll
        for (int mt = 0; mt < 2; ++mt)
#pragma unroll
            for (int nt = 0; nt < 4; ++nt) {
                acc[mt][nt] = __builtin_amdgcn_mfma_f32_16x16x32_bf16(ah[mt], bh[nt], acc[mt][nt], 0, 0, 0);
                acc[mt][nt] = __builtin_amdgcn_mfma_f32_16x16x32_bf16(ah[mt], bl[nt], acc[mt][nt], 0, 0, 0);
                acc[mt][nt] = __builtin_amdgcn_mfma_f32_16x16x32_bf16(al[mt], bh[nt], acc[mt][nt], 0, 0, 0);
            }
    }

#pragma unroll
    for (int mt = 0; mt < 2; ++mt)
#pragma unroll
        for (int r = 0; r < 4; ++r) {
            int row = m_base + mt * 16 + quad * 4 + r;
#pragma unroll
            for (int nt = 0; nt < 4; ++nt) {
                int col = wave * 64 + nt * 16 + l16;
                C[(size_t)row * EMB + col] = acc[mt][nt][r];
            }
        }
}

// ---------------- shared device pieces for fused kernels ----------------

// aggregate this block's 32 nodes into S (f32), wave-per-node (8 nodes/wave serial),
// lane owns 4 consecutive dims. Gather loop unrolled x2 for MLP.
static __device__ __forceinline__ void agg_to_lds(
    float (*S)[SROW], int nb, int wave, int lane,
    const float* __restrict__ Fin,
    const int* __restrict__ row_off, const int* __restrict__ csr_src,
    const float* __restrict__ csr_norm, const float* __restrict__ dinv,
    const float* __restrict__ bagg, int relu)
{
    const float4* F4 = (const float4*)Fin;
    int d0 = lane * 4;
    float4 bb = *(const float4*)(bagg + d0);
#pragma unroll 2
    for (int t = 0; t < 8; ++t) {
        int node = nb + wave * 8 + t;
        float dv = dinv[node];
        float ws = dv * dv;
        float4 sv = F4[(size_t)node * 64 + lane];
        float a0 = bb.x + ws * sv.x;
        float a1 = bb.y + ws * sv.y;
        float a2 = bb.z + ws * sv.z;
        float a3 = bb.w + ws * sv.w;
        int j = row_off[node], je = row_off[node + 1];
        for (; j + 1 < je; j += 2) {
            int   s0 = csr_src[j],  s1 = csr_src[j + 1];
            float w0 = csr_norm[j], w1 = csr_norm[j + 1];
            float4 v0 = F4[(size_t)s0 * 64 + lane];
            float4 v1 = F4[(size_t)s1 * 64 + lane];
            a0 += w0 * v0.x + w1 * v1.x;
            a1 += w0 * v0.y + w1 * v1.y;
            a2 += w0 * v0.z + w1 * v1.z;
            a3 += w0 * v0.w + w1 * v1.w;
        }
        if (j < je) {
            int   s = csr_src[j];
            float w = csr_norm[j];
            float4 v = F4[(size_t)s * 64 + lane];
            a0 += w * v.x; a1 += w * v.y; a2 += w * v.z; a3 += w * v.w;
        }
        if (relu) {
            a0 = fmaxf(a0, 0.f); a1 = fmaxf(a1, 0.f);
            a2 = fmaxf(a2, 0.f); a3 = fmaxf(a3, 0.f);
        }
        float4 out; out.x = a0; out.y = a1; out.z = a2; out.w = a3;
        *(float4*)&S[wave * 8 + t][d0] = out;
    }
}

// one split-bf16 GEMM layer: acc = S[32x256] @ W (K=EMB), A from LDS, B from global pair
static __device__ __forceinline__ void gemm_layer(
    const float (*S)[SROW], int wave, int quad, int l16,
    const unsigned short* __restrict__ Wth,
    const unsigned short* __restrict__ Wtl,
    f32x4 acc[2][4])
{
#pragma unroll
    for (int mt = 0; mt < 2; ++mt)
#pragma unroll
        for (int nt = 0; nt < 4; ++nt) acc[mt][nt] = (f32x4){0.f, 0.f, 0.f, 0.f};

    for (int ks = 0; ks < EMB / 32; ++ks) {
        int k0 = ks * 32 + quad * 8;
        s16x8 ah[2], al[2], bh[4], bl[4];
#pragma unroll
        for (int nt = 0; nt < 4; ++nt) {
            int nn = wave * 64 + nt * 16 + l16;
            bh[nt] = *(const s16x8*)(Wth + (size_t)nn * EMB + k0);
            bl[nt] = *(const s16x8*)(Wtl + (size_t)nn * EMB + k0);
        }
#pragma unroll
        for (int mt = 0; mt < 2; ++mt) {
            float fv[8];
            *(float4*)(fv)     = *(const float4*)&S[mt * 16 + l16][k0];
            *(float4*)(fv + 4) = *(const float4*)&S[mt * 16 + l16][k0 + 4];
            split8(fv, ah[mt], al[mt]);
        }
#pragma unroll
        for (int mt = 0; mt < 2; ++mt)
#pragma unroll
            for (int nt = 0; nt < 4; ++nt) {
                acc[mt][nt] = __builtin_amdgcn_mfma_f32_16x16x32_bf16(ah[mt], bh[nt], acc[mt][nt], 0, 0, 0);
                acc[mt][nt] = __builtin_amdgcn_mfma_f32_16x16x32_bf16(ah[mt], bl[nt], acc[mt][nt], 0, 0, 0);
                acc[mt][nt] = __builtin_amdgcn_mfma_f32_16x16x32_bf16(al[mt], bh[nt], acc[mt][nt], 0, 0, 0);
            }
    }
}

// ---------------- fused conv: agg(Fin)+bias,relu -> LDS -> @W -> Fout (f32) ----------------

__global__ __launch_bounds__(256) void k_conv_fused(
    const float* __restrict__ Fin,
    const int* __restrict__ row_off, const int* __restrict__ csr_src,
    const float* __restrict__ csr_norm, const float* __restrict__ dinv,
    const float* __restrict__ bagg,
    const unsigned short* __restrict__ Wth, const unsigned short* __restrict__ Wtl,
    float* __restrict__ Fout)
{
    __shared__ float S[32][SROW];
    int tid  = threadIdx.x;
    int lane = tid & 63, wave = tid >> 6;
    int quad = lane >> 4, l16 = lane & 15;
    int nb   = blockIdx.x * 32;

    agg_to_lds(S, nb, wave, lane, Fin, row_off, csr_src, csr_norm, dinv, bagg, 1);
    __syncthreads();

    f32x4 acc[2][4];
    gemm_layer(S, wave, quad, l16, Wth, Wtl, acc);

#pragma unroll
    for (int mt = 0; mt < 2; ++mt)
#pragma unroll
        for (int r = 0; r < 4; ++r) {
            int row = nb + mt * 16 + quad * 4 + r;
#pragma unroll
            for (int nt = 0; nt < 4; ++nt) {
                int col = wave * 64 + nt * 16 + l16;
                Fout[(size_t)row * EMB + col] = acc[mt][nt][r];
            }
        }
}

// ---------------- fused tail: agg(Fin)+b2 -> LDS -> 3 MLP layers -> out ----------------

__global__ __launch_bounds__(256) void k_mlp_fused(
    const float* __restrict__ Fin,
    const int* __restrict__ row_off, const int* __restrict__ csr_src,
    const float* __restrict__ csr_norm, const float* __restrict__ dinv,
    const float* __restrict__ bagg,
    const unsigned short* __restrict__ Wth3, const unsigned short* __restrict__ Wtl3,
    const float* __restrict__ b3,
    const unsigned short* __restrict__ Wth4, const unsigned short* __restrict__ Wtl4,
    const float* __restrict__ b4,
    const unsigned short* __restrict__ Wth5, const unsigned short* __restrict__ Wtl5,
    const float* __restrict__ b5,
    float* __restrict__ out)
{
    __shared__ float S[32][SROW];
    int tid  = threadIdx.x;
    int lane = tid & 63, wave = tid >> 6;
    int quad = lane >> 4, l16 = lane & 15;
    int nb   = blockIdx.x * 32;

    agg_to_lds(S, nb, wave, lane, Fin, row_off, csr_src, csr_norm, dinv, bagg, 0);
    __syncthreads();

    f32x4 acc[2][4];

    // mlp1: relu(S @ W3 + b3) -> S
    gemm_layer(S, wave, quad, l16, Wth3, Wtl3, acc);
    __syncthreads();   // all reads of S done before overwrite
#pragma unroll
    for (int mt = 0; mt < 2; ++mt)
#pragma unroll
        for (int r = 0; r < 4; ++r) {
            int row = mt * 16 + quad * 4 + r;
#pragma unroll
            for (int nt = 0; nt < 4; ++nt) {
                int col = wave * 64 + nt * 16 + l16;
                S[row][col] = fmaxf(acc[mt][nt][r] + b3[col], 0.f);
            }
        }
    __syncthreads();

    // mlp2: relu(S @ W4 + b4) -> S
    gemm_layer(S, wave, quad, l16, Wth4, Wtl4, acc);
    __syncthreads();
#pragma unroll
    for (int mt = 0; mt < 2; ++mt)
#pragma unroll
        for (int r = 0; r < 4; ++r) {
            int row = mt * 16 + quad * 4 + r;
#pragma unroll
            for (int nt = 0; nt < 4; ++nt) {
                int col = wave * 64 + nt * 16 + l16;
                S[row][col] = fmaxf(acc[mt][nt][r] + b4[col], 0.f);
            }
        }
    __syncthreads();

    // mlp3: S @ W5 + b5 -> global out
    gemm_layer(S, wave, quad, l16, Wth5, Wtl5, acc);
#pragma unroll
    for (int mt = 0; mt < 2; ++mt)
#pragma unroll
        for (int r = 0; r < 4; ++r) {
            int row = nb + mt * 16 + quad * 4 + r;
#pragma unroll
            for (int nt = 0; nt < 4; ++nt) {
                int col = wave * 64 + nt * 16 + l16;
                out[(size_t)row * EMB + col] = acc[mt][nt][r] + b5[col];
            }
        }
}

// ---------------- launch (9 dispatches) ----------------

extern "C" void kernel_launch(void* const* d_in, const int* in_sizes, int n_in,
                              void* d_out, int out_size, void* d_ws, size_t ws_size,
                              hipStream_t stream) {
    const float* x  = (const float*)d_in[0];
    const int*   ei = (const int*)d_in[1];
    const int* src = ei;
    const int* dst = ei + N_EDGES;

    const float* w[6] = {
        (const float*)d_in[2], (const float*)d_in[4], (const float*)d_in[6],
        (const float*)d_in[8], (const float*)d_in[10], (const float*)d_in[12] };
    const float* b[6] = {
        (const float*)d_in[3], (const float*)d_in[5], (const float*)d_in[7],
        (const float*)d_in[9], (const float*)d_in[11], (const float*)d_in[13] };

    char* wsp = (char*)d_ws;
    auto alloc = [&](size_t bytes) {
        char* p = wsp; wsp += (bytes + 255) & ~(size_t)255; return p;
    };
    int*   deg      = (int*)alloc(N_NODES * 4);
    int*   cursor   = (int*)alloc(N_NODES * 4);
    int*   row_off  = (int*)alloc((N_NODES + 1) * 4);
    int*   csr_src  = (int*)alloc(N_EDGES * 4);
    float* csr_norm = (float*)alloc(N_EDGES * 4);
    float* dinv     = (float*)alloc(N_NODES * 4);
    unsigned short* wth[6];
    unsigned short* wtl[6];
    wth[0] = (unsigned short*)alloc(EMB * KPAD0 * 2);
    wtl[0] = (unsigned short*)alloc(EMB * KPAD0 * 2);
    for (int i = 1; i < 6; ++i) {
        wth[i] = (unsigned short*)alloc(EMB * EMB * 2);
        wtl[i] = (unsigned short*)alloc(EMB * EMB * 2);
    }
    float* FA = (float*)alloc((size_t)N_NODES * EMB * 4);   // ws f32 buffer
    float* FB = (float*)d_out;                               // d_out doubles as scratch

    const int NB_N = (N_NODES + 255) / 256;   // 79
    const int NB_E = (N_EDGES + 255) / 256;   // 1250
    const int MB   = N_NODES / 32;            // 625

    // CSR build
    k_init<<<NB_N, 256, 0, stream>>>(deg, cursor, N_NODES);
    k_deg<<<NB_E, 256, 0, stream>>>(dst, deg, N_EDGES);
    k_scan<<<1, 1024, 0, stream>>>(deg, row_off, dinv, N_NODES);
    k_scatter<<<NB_E, 256, 0, stream>>>(src, dst, row_off, cursor, dinv,
                                        csr_src, csr_norm, N_EDGES);

    // weights: transpose + hi/lo split, one dispatch
    WSplitArgs wa;
    for (int i = 0; i < 6; ++i) { wa.w[i] = w[i]; wa.th[i] = wth[i]; wa.tl[i] = wtl[i]; }
    k_wsplit_all<<<320, 256, 0, stream>>>(wa);

    // conv0 gemm: x @ W0 -> FA
    k_gemm0<<<MB, 256, 0, stream>>>(x, wth[0], wtl[0], FA);
    // conv1: agg(FA)+b0,relu -> @W1 -> FB
    k_conv_fused<<<MB, 256, 0, stream>>>(FA, row_off, csr_src, csr_norm, dinv,
                                         b[0], wth[1], wtl[1], FB);
    // conv2: agg(FB)+b1,relu -> @W2 -> FA
    k_conv_fused<<<MB, 256, 0, stream>>>(FB, row_off, csr_src, csr_norm, dinv,
                                         b[1], wth[2], wtl[2], FA);
    // tail: agg(FA)+b2 -> mlp1(relu) -> mlp2(relu) -> mlp3 -> d_out
    k_mlp_fused<<<MB, 256, 0, stream>>>(FA, row_off, csr_src, csr_norm, dinv,
                                        b[2],
                                        wth[3], wtl[3], b[3],
                                        wth[4], wtl[4], b[4],
                                        wth[5], wtl[5], b[5],
                                        FB);
}